// Round 8
// baseline (111669.299 us; speedup 1.0000x reference)
//
#include <hip/hip_runtime.h>
#include <hip/hip_bf16.h>

typedef __hip_bfloat16 bf16;
typedef __attribute__((ext_vector_type(8))) short short8;
typedef __attribute__((ext_vector_type(4))) float floatx4;

#define DM   768
#define NH   12
#define DH   64
#define DFF  3072
#define TS   4096
#define NB   2
#define MTOK (NB * TS)
#define EPS  1e-5f
#define NEG  -30000.0f

__device__ __forceinline__ float b2f(bf16 v)  { return __bfloat162float(v); }
__device__ __forceinline__ bf16  f2b(float v) { return __float2bfloat16(v); }
__device__ __forceinline__ short sbf(float x) { bf16 b = __float2bfloat16(x); return *(short*)&b; }
__device__ __forceinline__ float sh2f(short s) {
    union { unsigned u; float f; } c; c.u = ((unsigned)(unsigned short)s) << 16; return c.f;
}
__device__ __forceinline__ float ldf(const float* p) { return *p; }
__device__ __forceinline__ float ldf(const bf16*  p) { return b2f(*p); }
__device__ __forceinline__ void stf(float* p, float v) { *p = v; }
__device__ __forceinline__ void stf(bf16*  p, float v) { *p = f2b(v); }

// ---------------------------------------------------------------------------
// MFMA GEMM (PROVEN round 6).
// ---------------------------------------------------------------------------
template <int RELU, typename TA>
__global__ __launch_bounds__(256)
void gemm_mfma(const TA* __restrict__ A, int lda, const bf16* __restrict__ Wt,
               const float* __restrict__ bias, bf16* __restrict__ C, int ldc,
               int N, int K)
{
    constexpr int LDT = 40;
    __shared__ __align__(16) short As[128 * LDT];
    __shared__ __align__(16) short Bs[128 * LDT];

    const int tid  = threadIdx.x;
    const int wave = tid >> 6, lane = tid & 63;
    const int wx = wave & 1, wy = wave >> 1;
    const int quad = lane >> 4, fn = lane & 15;
    const int bm = blockIdx.y * 128, bn = blockIdx.x * 128;

    floatx4 acc[4][4] = {};
    const int sr = tid >> 2, sc8 = (tid & 3) * 8;

    for (int kk = 0; kk < K; kk += 32) {
        __syncthreads();
        if constexpr (sizeof(TA) == 2) {
            *(short8*)&As[sr * LDT + sc8] =
                *(const short8*)&A[(size_t)(bm + sr) * lda + kk + sc8];
            *(short8*)&As[(sr + 64) * LDT + sc8] =
                *(const short8*)&A[(size_t)(bm + sr + 64) * lda + kk + sc8];
        } else {
            const float* p0 = (const float*)A + (size_t)(bm + sr) * lda + kk + sc8;
            const float* p1 = (const float*)A + (size_t)(bm + sr + 64) * lda + kk + sc8;
            float4 a0 = *(const float4*)p0, a1 = *(const float4*)(p0 + 4);
            float4 c0 = *(const float4*)p1, c1 = *(const float4*)(p1 + 4);
            short8 v0, v1;
            v0[0]=sbf(a0.x); v0[1]=sbf(a0.y); v0[2]=sbf(a0.z); v0[3]=sbf(a0.w);
            v0[4]=sbf(a1.x); v0[5]=sbf(a1.y); v0[6]=sbf(a1.z); v0[7]=sbf(a1.w);
            v1[0]=sbf(c0.x); v1[1]=sbf(c0.y); v1[2]=sbf(c0.z); v1[3]=sbf(c0.w);
            v1[4]=sbf(c1.x); v1[5]=sbf(c1.y); v1[6]=sbf(c1.z); v1[7]=sbf(c1.w);
            *(short8*)&As[sr * LDT + sc8] = v0;
            *(short8*)&As[(sr + 64) * LDT + sc8] = v1;
        }
        *(short8*)&Bs[sr * LDT + sc8] =
            *(const short8*)&Wt[(size_t)(bn + sr) * K + kk + sc8];
        *(short8*)&Bs[(sr + 64) * LDT + sc8] =
            *(const short8*)&Wt[(size_t)(bn + sr + 64) * K + kk + sc8];
        __syncthreads();

        short8 af[4], bfr[4];
        #pragma unroll
        for (int i = 0; i < 4; ++i) {
            af[i]  = *(const short8*)&As[(wy * 64 + i * 16 + fn) * LDT + quad * 8];
            bfr[i] = *(const short8*)&Bs[(wx * 64 + i * 16 + fn) * LDT + quad * 8];
        }
        #pragma unroll
        for (int i = 0; i < 4; ++i)
            #pragma unroll
            for (int j = 0; j < 4; ++j)
                acc[i][j] = __builtin_amdgcn_mfma_f32_16x16x32_bf16(
                    af[i], bfr[j], acc[i][j], 0, 0, 0);
    }

    #pragma unroll
    for (int j = 0; j < 4; ++j) {
        const int n = bn + wx * 64 + j * 16 + fn;
        const float bv = bias[n];
        #pragma unroll
        for (int i = 0; i < 4; ++i) {
            #pragma unroll
            for (int rg = 0; rg < 4; ++rg) {
                const int m = bm + wy * 64 + i * 16 + quad * 4 + rg;
                float v = acc[i][j][rg] + bv;
                if (RELU) v = fmaxf(v, 0.f);
                C[(size_t)m * ldc + n] = f2b(v);
            }
        }
    }
}

// ---------------------------------------------------------------------------
// Scalar flash attention (PROVEN round 6) — in-place into Q-band.
// ---------------------------------------------------------------------------
__global__ __launch_bounds__(64)
void attn_scalar(bf16* __restrict__ QKV)
{
    const int gid  = blockIdx.x;
    const int q    = gid & (TS - 1);
    const int hb   = gid >> 12;
    const int h    = hb % NH;
    const int b    = hb / NH;
    const int lane = threadIdx.x;

    const size_t rowbase = (size_t)(b * TS) * 2304 + h * 64 + lane;
    const float qv = b2f(QKV[rowbase + (size_t)q * 2304]) * 0.125f;

    float m = -1e30f, l = 0.f, acc = 0.f;
    for (int k = 0; k <= q; ++k) {
        const size_t off = rowbase + (size_t)k * 2304;
        float s = qv * b2f(QKV[off + 768]);
        #pragma unroll
        for (int d = 32; d > 0; d >>= 1) s += __shfl_xor(s, d, 64);
        const float mn = fmaxf(m, s);
        const float p  = __expf(s - mn);
        const float cr = __expf(m - mn);
        const float vv = b2f(QKV[off + 1536]);
        l   = l * cr + p;
        acc = acc * cr + p * vv;
        m   = mn;
    }
    QKV[rowbase + (size_t)q * 2304] = f2b(acc / l);
}

// ---------------------------------------------------------------------------
// HARDENED MFMA attention candidate (under test; output -> scratch Hb).
// vs round-7 attn_mix: sentinel -3e4 (not -1e30), exp(min(.,0)) clamps,
// l floored. NaN/inf structurally impossible: every exp arg <= 0.
// ---------------------------------------------------------------------------
__global__ __launch_bounds__(256)
void attn_mix2(const bf16* __restrict__ QKV, bf16* __restrict__ Out)
{
    __shared__ __align__(16) short Ks[32 * 72];
    __shared__ __align__(16) short Vt[64 * 40];
    __shared__ __align__(16) short Ps[4][16 * 40];

    const int tid  = threadIdx.x;
    const int wave = tid >> 6, lane = tid & 63;
    const int quad = lane >> 4, fn = lane & 15;
    const int bh = blockIdx.y;
    const int b = bh / NH, h = bh % NH;
    const int q0 = (gridDim.x - 1 - blockIdx.x) * 64;
    const int nt = q0 / 32 + 2;

    const size_t rowQ = (size_t)(b * TS + q0 + wave * 16 + fn) * 2304 + h * 64;
    const short8 qa0 = *(const short8*)&QKV[rowQ + quad * 8];
    const short8 qa1 = *(const short8*)&QKV[rowQ + 32 + quad * 8];

    float m[4] = {NEG, NEG, NEG, NEG};
    float l[4] = {0.f, 0.f, 0.f, 0.f};
    floatx4 o[4] = {};

    const int sk = tid >> 3, sc8 = (tid & 7) * 8;
    const int vd = tid & 63, vk0 = tid >> 6;

    for (int t = 0; t < nt; ++t) {
        const int kk0 = t * 32;
        __syncthreads();
        *(short8*)&Ks[sk * 72 + sc8] =
            *(const short8*)&QKV[(size_t)(b * TS + kk0 + sk) * 2304 + 768 + h * 64 + sc8];
        #pragma unroll
        for (int i = 0; i < 8; ++i) {
            const int k = vk0 + i * 4;
            Vt[vd * 40 + k] =
                QKV[(size_t)(b * TS + kk0 + k) * 2304 + 1536 + h * 64 + vd];
        }
        __syncthreads();

        const short8 b00 = *(const short8*)&Ks[fn * 72 + quad * 8];
        const short8 b01 = *(const short8*)&Ks[fn * 72 + 32 + quad * 8];
        const short8 b10 = *(const short8*)&Ks[(16 + fn) * 72 + quad * 8];
        const short8 b11 = *(const short8*)&Ks[(16 + fn) * 72 + 32 + quad * 8];
        floatx4 s0 = {}, s1 = {};
        s0 = __builtin_amdgcn_mfma_f32_16x16x32_bf16(qa0, b00, s0, 0, 0, 0);
        s0 = __builtin_amdgcn_mfma_f32_16x16x32_bf16(qa1, b01, s0, 0, 0, 0);
        s1 = __builtin_amdgcn_mfma_f32_16x16x32_bf16(qa0, b10, s1, 0, 0, 0);
        s1 = __builtin_amdgcn_mfma_f32_16x16x32_bf16(qa1, b11, s1, 0, 0, 0);

        const int qg = q0 + wave * 16 + quad * 4;
        #pragma unroll
        for (int rg = 0; rg < 4; ++rg) {
            float v0 = (kk0 + fn      <= qg + rg) ? s0[rg] * 0.125f : NEG;
            float v1 = (kk0 + 16 + fn <= qg + rg) ? s1[rg] * 0.125f : NEG;
            float mx = fmaxf(v0, v1);
            mx = fmaxf(mx, __shfl_xor(mx, 1, 64));
            mx = fmaxf(mx, __shfl_xor(mx, 2, 64));
            mx = fmaxf(mx, __shfl_xor(mx, 4, 64));
            mx = fmaxf(mx, __shfl_xor(mx, 8, 64));
            const float mn2 = fmaxf(m[rg], mx);
            const float p0 = __expf(fminf(v0 - mn2, 0.f));
            const float p1 = __expf(fminf(v1 - mn2, 0.f));
            const float cr = __expf(fminf(m[rg] - mn2, 0.f));
            m[rg] = mn2;
            float ps = p0 + p1;
            ps += __shfl_xor(ps, 1, 64);
            ps += __shfl_xor(ps, 2, 64);
            ps += __shfl_xor(ps, 4, 64);
            ps += __shfl_xor(ps, 8, 64);
            l[rg] = l[rg] * cr + ps;
            #pragma unroll
            for (int cb = 0; cb < 4; ++cb) o[cb][rg] *= cr;
            Ps[wave][(quad * 4 + rg) * 40 + fn]      = sbf(p0);
            Ps[wave][(quad * 4 + rg) * 40 + 16 + fn] = sbf(p1);
        }
        __syncthreads();

        // scalar PV from Ps/Vt
        #pragma unroll
        for (int k8 = 0; k8 < 4; ++k8) {
            float pv[4][8];
            #pragma unroll
            for (int rg = 0; rg < 4; ++rg) {
                const short8 pr = *(const short8*)&Ps[wave][(quad * 4 + rg) * 40 + k8 * 8];
                #pragma unroll
                for (int j = 0; j < 8; ++j) pv[rg][j] = sh2f(pr[j]);
            }
            #pragma unroll
            for (int cb = 0; cb < 4; ++cb) {
                const short8 vr = *(const short8*)&Vt[(cb * 16 + fn) * 40 + k8 * 8];
                #pragma unroll
                for (int rg = 0; rg < 4; ++rg)
                    #pragma unroll
                    for (int j = 0; j < 8; ++j)
                        o[cb][rg] += pv[rg][j] * sh2f(vr[j]);
            }
        }
    }

    #pragma unroll
    for (int cb = 0; cb < 4; ++cb)
        #pragma unroll
        for (int rg = 0; rg < 4; ++rg) {
            const size_t row = (size_t)(b * TS + q0 + wave * 16 + quad * 4 + rg);
            const float li = fmaxf(l[rg], 1e-20f);
            Out[row * DM + h * 64 + cb * 16 + fn] = f2b(o[cb][rg] / li);
        }
}

// ---------------------------------------------------------------------------
// Diagnostics: compare mix2 (Hb) vs proven scalar output (Q-band); encode
// result in spin-kernel DURATIONS readable from dur_us / rocprof.
//   diag[0] = max category: 0 ok | 1 diff>0.25 | 2 |val|>1e3 | 3 inf | 4 nan
//   diag[1] = first bad row (min), 100000 if none
// dur decode: total ~= 30ms base + cat*20ms + first_bad_row*1us.
// ---------------------------------------------------------------------------
__global__ void diag_init(int* diag)
{ if (threadIdx.x == 0) { diag[0] = 0; diag[1] = 100000; } }

__global__ __launch_bounds__(256)
void diag_compare(const bf16* __restrict__ mix, const bf16* __restrict__ qkv,
                  int* diag)
{
    const int row = blockIdx.x;
    int cat = 0;
    for (int j = 0; j < 3; ++j) {
        const int col = threadIdx.x + j * 256;
        const float a = b2f(mix[(size_t)row * DM + col]);
        const float bb = b2f(qkv[(size_t)row * 2304 + col]);
        int e = 0;
        if (fabsf(a - bb) > 0.25f) e = 1;
        if (fabsf(a) > 1e3f)       e = 2;
        if (fabsf(a) > 3e38f)      e = 3;
        if (a != a)                e = 4;
        cat = max(cat, e);
    }
    if (cat > 0) { atomicMax(&diag[0], cat); atomicMin(&diag[1], row); }
}

__global__ void diag_spin_calib()   // always 15 ms @ 100 MHz realtime clock
{
    if (threadIdx.x == 0) {
        unsigned long long t0 = __builtin_amdgcn_s_memrealtime();
        while (__builtin_amdgcn_s_memrealtime() - t0 < 1500000ull) {}
    }
}
__global__ void diag_spin_cat(const int* diag)   // cat * 20 ms
{
    if (threadIdx.x == 0) {
        unsigned long long n = (unsigned long long)diag[0] * 2000000ull;
        unsigned long long t0 = __builtin_amdgcn_s_memrealtime();
        while (__builtin_amdgcn_s_memrealtime() - t0 < n) {}
    }
}
__global__ void diag_spin_row(const int* diag)   // first_bad_row * 1 us
{
    if (threadIdx.x == 0) {
        unsigned long long n = (diag[0] > 0 && diag[1] < 100000)
                             ? (unsigned long long)diag[1] * 100ull : 0ull;
        unsigned long long t0 = __builtin_amdgcn_s_memrealtime();
        while (__builtin_amdgcn_s_memrealtime() - t0 < n) {}
    }
}

// ---------------------------------------------------------------------------
__global__ __launch_bounds__(256)
void transW(const float* __restrict__ W, bf16* __restrict__ Wt, int K, int N)
{
    __shared__ float t[32][33];
    const int k0 = blockIdx.x * 32, n0 = blockIdx.y * 32;
    const int tx = threadIdx.x, ty = threadIdx.y;
    #pragma unroll
    for (int i = 0; i < 4; ++i)
        t[ty + i * 8][tx] = W[(size_t)(k0 + ty + i * 8) * N + n0 + tx];
    __syncthreads();
    #pragma unroll
    for (int i = 0; i < 4; ++i)
        Wt[(size_t)(n0 + ty + i * 8) * K + k0 + tx] = f2b(t[tx][ty + i * 8]);
}

__global__ __launch_bounds__(256)
void pack_bias(const float* __restrict__ bq, const float* __restrict__ bk,
               const float* __restrict__ bv, float* __restrict__ out)
{
    const int i = blockIdx.x * 256 + threadIdx.x;
    if (i < 3 * DM)
        out[i] = (i < DM) ? bq[i] : (i < 2 * DM) ? bk[i - DM] : bv[i - 2 * DM];
}

template <typename T1, typename T2, typename TOUT>
__global__ __launch_bounds__(256)
void add_ln(const T1* __restrict__ a, const T2* __restrict__ r, int ldr,
            const float* __restrict__ gamma, const float* __restrict__ beta,
            TOUT* __restrict__ out)
{
    const int row = blockIdx.x;
    const size_t offa = (size_t)row * DM;
    const size_t offr = (size_t)row * ldr;
    const int tid = threadIdx.x;

    float v[3];
    float s = 0.f, s2 = 0.f;
    #pragma unroll
    for (int j = 0; j < 3; ++j) {
        const int i = tid + j * 256;
        const float t = ldf(a + offa + i) + ldf(r + offr + i);
        v[j] = t; s += t; s2 += t * t;
    }
    __shared__ float red[256], red2[256];
    red[tid] = s; red2[tid] = s2;
    __syncthreads();
    #pragma unroll
    for (int st = 128; st > 0; st >>= 1) {
        if (tid < st) { red[tid] += red[tid + st]; red2[tid] += red2[tid + st]; }
        __syncthreads();
    }
    const float mu   = red[0] * (1.f / DM);
    const float var  = red2[0] * (1.f / DM) - mu * mu;
    const float rstd = rsqrtf(var + EPS);
    #pragma unroll
    for (int j = 0; j < 3; ++j) {
        const int i = tid + j * 256;
        stf(out + offa + i, (v[j] - mu) * rstd * gamma[i] + beta[i]);
    }
}

// ---------------------------------------------------------------------------
extern "C" void kernel_launch(void* const* d_in, const int* in_sizes, int n_in,
                              void* d_out, int out_size, void* d_ws, size_t ws_size,
                              hipStream_t stream)
{
    (void)in_sizes; (void)n_in; (void)out_size; (void)ws_size;

    const float* x   = (const float*)d_in[0];
    const float* wq  = (const float*)d_in[1];  const float* bq  = (const float*)d_in[2];
    const float* wk  = (const float*)d_in[3];  const float* bk  = (const float*)d_in[4];
    const float* wv  = (const float*)d_in[5];  const float* bv  = (const float*)d_in[6];
    const float* wo  = (const float*)d_in[7];  const float* bo  = (const float*)d_in[8];
    const float* w1  = (const float*)d_in[9];  const float* b1  = (const float*)d_in[10];
    const float* w2  = (const float*)d_in[11]; const float* b2  = (const float*)d_in[12];
    const float* g1  = (const float*)d_in[13]; const float* be1 = (const float*)d_in[14];
    const float* g2  = (const float*)d_in[15]; const float* be2 = (const float*)d_in[16];

    // ws layout (bf16 elems), ~59.8 MB + 8 B diag:
    //   QKVb 3S | Hb S | wbuf 2*DFF*DM | bqkv fp32[2304] | diag int[2]
    const size_t S = (size_t)MTOK * DM;
    bf16* QKVb = (bf16*)d_ws;
    bf16* Hb   = QKVb + 3 * S;
    bf16* wbuf = Hb + S;
    float* bqkv = (float*)(wbuf + (size_t)2 * DFF * DM);
    int*  diag = (int*)(bqkv + 3 * DM);
    bf16* F1 = QKVb;
    bf16* Yb = QKVb + 2 * S;
    bf16* AttnO = QKVb;           // Q-band, lda 2304
    bf16* Pb = QKVb + DM;         // K-band

    const dim3 tblk(32, 8);
    const dim3 blk(256);

    // QKV projection
    transW<<<dim3(24, 24), tblk, 0, stream>>>(wq, wbuf,                    DM, DM);
    transW<<<dim3(24, 24), tblk, 0, stream>>>(wk, wbuf + (size_t)DM * DM,  DM, DM);
    transW<<<dim3(24, 24), tblk, 0, stream>>>(wv, wbuf + (size_t)2*DM*DM,  DM, DM);
    pack_bias<<<dim3(9), blk, 0, stream>>>(bq, bk, bv, bqkv);
    gemm_mfma<0, float><<<dim3(18, 64), blk, 0, stream>>>(
        x, DM, wbuf, bqkv, QKVb, 3 * DM, 3 * DM, DM);

    // --- diagnostics: hardened MFMA attention into Hb (reads pristine Q) ---
    attn_mix2<<<dim3(64, NB * NH), blk, 0, stream>>>(QKVb, Hb);

    // proven scalar attention (in-place Q-band) -> real pipeline
    attn_scalar<<<dim3(NB * NH * TS), dim3(64), 0, stream>>>(QKVb);

    // compare + encode into spin durations
    diag_init<<<dim3(1), dim3(64), 0, stream>>>(diag);
    diag_compare<<<dim3(MTOK), blk, 0, stream>>>(Hb, QKVb, diag);
    diag_spin_calib<<<dim3(1), dim3(64), 0, stream>>>();
    diag_spin_cat<<<dim3(1), dim3(64), 0, stream>>>(diag);
    diag_spin_row<<<dim3(1), dim3(64), 0, stream>>>(diag);

    // O-projection (Q-band -> K-band), LN1 -> Hb (overwrites scratch)
    transW<<<dim3(24, 24), tblk, 0, stream>>>(wo, wbuf, DM, DM);
    gemm_mfma<0, bf16><<<dim3(6, 64), blk, 0, stream>>>(
        AttnO, 3 * DM, wbuf, bo, Pb, 3 * DM, DM, DM);
    add_ln<float, bf16, bf16><<<dim3(MTOK), blk, 0, stream>>>(
        x, Pb, 3 * DM, g1, be1, Hb);

    // FFN
    transW<<<dim3(24, 96), tblk, 0, stream>>>(w1, wbuf, DM, DFF);
    bf16* w2t = wbuf + (size_t)DFF * DM;
    transW<<<dim3(96, 24), tblk, 0, stream>>>(w2, w2t, DFF, DM);
    for (int m0 = 0; m0 < MTOK; m0 += 4096) {
        gemm_mfma<1, bf16><<<dim3(24, 32), blk, 0, stream>>>(
            Hb + (size_t)m0 * DM, DM, wbuf, b1, F1, DFF, DFF, DM);
        gemm_mfma<0, bf16><<<dim3(6, 32), blk, 0, stream>>>(
            F1, DFF, w2t, b2, Yb + (size_t)m0 * DM, DM, DM, DFF);
    }

    add_ln<bf16, bf16, float><<<dim3(MTOK), blk, 0, stream>>>(
        Hb, Yb, DM, g2, be2, (float*)d_out);
}

// Round 9
// 101730.713 us; speedup vs baseline: 1.0977x; 1.0977x over previous
//
#include <hip/hip_runtime.h>
#include <hip/hip_bf16.h>

typedef __hip_bfloat16 bf16;
typedef __attribute__((ext_vector_type(8))) short short8;
typedef __attribute__((ext_vector_type(4))) float floatx4;

#define DM   768
#define NH   12
#define DH   64
#define DFF  3072
#define TS   4096
#define NB   2
#define MTOK (NB * TS)
#define EPS  1e-5f
#define NEG  -30000.0f

__device__ __forceinline__ float b2f(bf16 v)  { return __bfloat162float(v); }
__device__ __forceinline__ bf16  f2b(float v) { return __float2bfloat16(v); }
__device__ __forceinline__ short sbf(float x) { bf16 b = __float2bfloat16(x); return *(short*)&b; }
__device__ __forceinline__ float ldf(const float* p) { return *p; }
__device__ __forceinline__ float ldf(const bf16*  p) { return b2f(*p); }
__device__ __forceinline__ void stf(float* p, float v) { *p = v; }
__device__ __forceinline__ void stf(bf16*  p, float v) { *p = f2b(v); }

// ---------------------------------------------------------------------------
// MFMA GEMM (PROVEN round 6).
// ---------------------------------------------------------------------------
template <int RELU, typename TA>
__global__ __launch_bounds__(256)
void gemm_mfma(const TA* __restrict__ A, int lda, const bf16* __restrict__ Wt,
               const float* __restrict__ bias, bf16* __restrict__ C, int ldc,
               int N, int K)
{
    constexpr int LDT = 40;
    __shared__ __align__(16) short As[128 * LDT];
    __shared__ __align__(16) short Bs[128 * LDT];

    const int tid  = threadIdx.x;
    const int wave = tid >> 6, lane = tid & 63;
    const int wx = wave & 1, wy = wave >> 1;
    const int quad = lane >> 4, fn = lane & 15;
    const int bm = blockIdx.y * 128, bn = blockIdx.x * 128;

    floatx4 acc[4][4] = {};
    const int sr = tid >> 2, sc8 = (tid & 3) * 8;

    for (int kk = 0; kk < K; kk += 32) {
        __syncthreads();
        if constexpr (sizeof(TA) == 2) {
            *(short8*)&As[sr * LDT + sc8] =
                *(const short8*)&A[(size_t)(bm + sr) * lda + kk + sc8];
            *(short8*)&As[(sr + 64) * LDT + sc8] =
                *(const short8*)&A[(size_t)(bm + sr + 64) * lda + kk + sc8];
        } else {
            const float* p0 = (const float*)A + (size_t)(bm + sr) * lda + kk + sc8;
            const float* p1 = (const float*)A + (size_t)(bm + sr + 64) * lda + kk + sc8;
            float4 a0 = *(const float4*)p0, a1 = *(const float4*)(p0 + 4);
            float4 c0 = *(const float4*)p1, c1 = *(const float4*)(p1 + 4);
            short8 v0, v1;
            v0[0]=sbf(a0.x); v0[1]=sbf(a0.y); v0[2]=sbf(a0.z); v0[3]=sbf(a0.w);
            v0[4]=sbf(a1.x); v0[5]=sbf(a1.y); v0[6]=sbf(a1.z); v0[7]=sbf(a1.w);
            v1[0]=sbf(c0.x); v1[1]=sbf(c0.y); v1[2]=sbf(c0.z); v1[3]=sbf(c0.w);
            v1[4]=sbf(c1.x); v1[5]=sbf(c1.y); v1[6]=sbf(c1.z); v1[7]=sbf(c1.w);
            *(short8*)&As[sr * LDT + sc8] = v0;
            *(short8*)&As[(sr + 64) * LDT + sc8] = v1;
        }
        *(short8*)&Bs[sr * LDT + sc8] =
            *(const short8*)&Wt[(size_t)(bn + sr) * K + kk + sc8];
        *(short8*)&Bs[(sr + 64) * LDT + sc8] =
            *(const short8*)&Wt[(size_t)(bn + sr + 64) * K + kk + sc8];
        __syncthreads();

        short8 af[4], bfr[4];
        #pragma unroll
        for (int i = 0; i < 4; ++i) {
            af[i]  = *(const short8*)&As[(wy * 64 + i * 16 + fn) * LDT + quad * 8];
            bfr[i] = *(const short8*)&Bs[(wx * 64 + i * 16 + fn) * LDT + quad * 8];
        }
        #pragma unroll
        for (int i = 0; i < 4; ++i)
            #pragma unroll
            for (int j = 0; j < 4; ++j)
                acc[i][j] = __builtin_amdgcn_mfma_f32_16x16x32_bf16(
                    af[i], bfr[j], acc[i][j], 0, 0, 0);
    }

    #pragma unroll
    for (int j = 0; j < 4; ++j) {
        const int n = bn + wx * 64 + j * 16 + fn;
        const float bv = bias[n];
        #pragma unroll
        for (int i = 0; i < 4; ++i) {
            #pragma unroll
            for (int rg = 0; rg < 4; ++rg) {
                const int m = bm + wy * 64 + i * 16 + quad * 4 + rg;
                float v = acc[i][j][rg] + bv;
                if (RELU) v = fmaxf(v, 0.f);
                C[(size_t)m * ldc + n] = f2b(v);
            }
        }
    }
}

// ---------------------------------------------------------------------------
// Scalar flash attention (PROVEN) — in-place into Q-band. Real pipeline path.
// ---------------------------------------------------------------------------
__global__ __launch_bounds__(64)
void attn_scalar(bf16* __restrict__ QKV)
{
    const int gid  = blockIdx.x;
    const int q    = gid & (TS - 1);
    const int hb   = gid >> 12;
    const int h    = hb % NH;
    const int b    = hb / NH;
    const int lane = threadIdx.x;

    const size_t rowbase = (size_t)(b * TS) * 2304 + h * 64 + lane;
    const float qv = b2f(QKV[rowbase + (size_t)q * 2304]) * 0.125f;

    float m = -1e30f, l = 0.f, acc = 0.f;
    for (int k = 0; k <= q; ++k) {
        const size_t off = rowbase + (size_t)k * 2304;
        float s = qv * b2f(QKV[off + 768]);
        #pragma unroll
        for (int d = 32; d > 0; d >>= 1) s += __shfl_xor(s, d, 64);
        const float mn = fmaxf(m, s);
        const float p  = __expf(s - mn);
        const float cr = __expf(m - mn);
        const float vv = b2f(QKV[off + 1536]);
        l   = l * cr + p;
        acc = acc * cr + p * vv;
        m   = mn;
    }
    QKV[rowbase + (size_t)q * 2304] = f2b(acc / l);
}

// ---------------------------------------------------------------------------
// attn_v2 — m120-VERIFIED construct classes only (candidate, -> Hb):
//  * MFMA QK^T; results consumed ONLY by VALU + LDS store (GEMM-epilogue class)
//  * softmax computed FROM LDS (lane owns row lane>>2, 8-key slice);
//    shuffles touch only LDS-loaded VALU data (attn_scalar-proven class)
//  * P -> LDS (bf16, A-frag layout); PV via MFMA; per-tile accumulator
//    rescale via VALU with alpha from LDS (m120 pattern)
//  * NO cross-lane ops on MFMA-written registers (round-8 suspect class)
// ---------------------------------------------------------------------------
__global__ __launch_bounds__(256)
void attn_v2(const bf16* __restrict__ QKV, bf16* __restrict__ Out)
{
    __shared__ __align__(16) short Ks[32 * 72];      // [key][d]
    __shared__ __align__(16) short Vt[64 * 40];      // [d][key]
    __shared__ __align__(16) float Ss[4][16 * 36];   // per-wave S [q][key] fp32
    __shared__ __align__(16) short Ps[4][16 * 40];   // per-wave P [q][key] bf16
    __shared__ float Al[4][16];                      // per-row alpha
    __shared__ float Ll[4][16];                      // per-row l

    const int tid  = threadIdx.x;
    const int wave = tid >> 6, lane = tid & 63;
    const int quad = lane >> 4, fn = lane & 15;
    const int bh = blockIdx.y;
    const int b = bh / NH, h = bh % NH;
    const int q0 = (gridDim.x - 1 - blockIdx.x) * 64;
    const int nt = q0 / 32 + 2;

    const int orow = lane >> 2;        // softmax: row this lane owns
    const int okey = (lane & 3) * 8;   // 8-key slice

    const size_t rowQ = (size_t)(b * TS + q0 + wave * 16 + fn) * 2304 + h * 64;
    const short8 qa0 = *(const short8*)&QKV[rowQ + quad * 8];
    const short8 qa1 = *(const short8*)&QKV[rowQ + 32 + quad * 8];

    float mrow = NEG, lrow = 0.f;      // replicated across 4 sibling lanes
    floatx4 o[4] = {};

    const int sk = tid >> 3, sc8 = (tid & 7) * 8;
    const int vd = tid & 63, vk0 = tid >> 6;

    for (int t = 0; t < nt; ++t) {
        const int kk0 = t * 32;
        __syncthreads();
        *(short8*)&Ks[sk * 72 + sc8] =
            *(const short8*)&QKV[(size_t)(b * TS + kk0 + sk) * 2304 + 768 + h * 64 + sc8];
        #pragma unroll
        for (int i = 0; i < 8; ++i) {
            const int k = vk0 + i * 4;
            Vt[vd * 40 + k] =
                QKV[(size_t)(b * TS + kk0 + k) * 2304 + 1536 + h * 64 + vd];
        }
        __syncthreads();

        // S = Q K^T (MFMA)
        const short8 b00 = *(const short8*)&Ks[fn * 72 + quad * 8];
        const short8 b01 = *(const short8*)&Ks[fn * 72 + 32 + quad * 8];
        const short8 b10 = *(const short8*)&Ks[(16 + fn) * 72 + quad * 8];
        const short8 b11 = *(const short8*)&Ks[(16 + fn) * 72 + 32 + quad * 8];
        floatx4 s0 = {}, s1 = {};
        s0 = __builtin_amdgcn_mfma_f32_16x16x32_bf16(qa0, b00, s0, 0, 0, 0);
        s0 = __builtin_amdgcn_mfma_f32_16x16x32_bf16(qa1, b01, s0, 0, 0, 0);
        s1 = __builtin_amdgcn_mfma_f32_16x16x32_bf16(qa0, b10, s1, 0, 0, 0);
        s1 = __builtin_amdgcn_mfma_f32_16x16x32_bf16(qa1, b11, s1, 0, 0, 0);

        // scale + mask in VALU, S -> LDS (epilogue-class consumption of MFMA)
        const int qg = q0 + wave * 16 + quad * 4;
        #pragma unroll
        for (int rg = 0; rg < 4; ++rg) {
            const float v0 = (kk0 + fn      <= qg + rg) ? s0[rg] * 0.125f : NEG;
            const float v1 = (kk0 + 16 + fn <= qg + rg) ? s1[rg] * 0.125f : NEG;
            Ss[wave][(quad * 4 + rg) * 36 + fn]      = v0;
            Ss[wave][(quad * 4 + rg) * 36 + 16 + fn] = v1;
        }
        __syncthreads();

        // LDS softmax
        float sv[8];
        *(float4*)&sv[0] = *(const float4*)&Ss[wave][orow * 36 + okey];
        *(float4*)&sv[4] = *(const float4*)&Ss[wave][orow * 36 + okey + 4];
        float mx = sv[0];
        #pragma unroll
        for (int j = 1; j < 8; ++j) mx = fmaxf(mx, sv[j]);
        mx = fmaxf(mx, __shfl_xor(mx, 1, 64));
        mx = fmaxf(mx, __shfl_xor(mx, 2, 64));
        const float mn2 = fmaxf(mrow, mx);
        float ps = 0.f;
        short8 pb;
        #pragma unroll
        for (int j = 0; j < 8; ++j) {
            const float p = __expf(fminf(sv[j] - mn2, 0.f));
            ps += p;
            pb[j] = sbf(p);
        }
        ps += __shfl_xor(ps, 1, 64);
        ps += __shfl_xor(ps, 2, 64);
        const float cr = __expf(fminf(mrow - mn2, 0.f));
        lrow = lrow * cr + ps;
        mrow = mn2;
        *(short8*)&Ps[wave][orow * 40 + okey] = pb;
        if ((lane & 3) == 0) { Al[wave][orow] = cr; Ll[wave][orow] = lrow; }
        __syncthreads();

        // rescale accumulator (alpha from LDS) + PV MFMA
        float al[4];
        #pragma unroll
        for (int rg = 0; rg < 4; ++rg) al[rg] = Al[wave][quad * 4 + rg];
        #pragma unroll
        for (int cb = 0; cb < 4; ++cb)
            #pragma unroll
            for (int rg = 0; rg < 4; ++rg) o[cb][rg] *= al[rg];
        const short8 pf = *(const short8*)&Ps[wave][fn * 40 + quad * 8];
        #pragma unroll
        for (int cb = 0; cb < 4; ++cb) {
            const short8 vf = *(const short8*)&Vt[(cb * 16 + fn) * 40 + quad * 8];
            o[cb] = __builtin_amdgcn_mfma_f32_16x16x32_bf16(pf, vf, o[cb], 0, 0, 0);
        }
    }

    float li[4];
    #pragma unroll
    for (int rg = 0; rg < 4; ++rg)
        li[rg] = 1.f / fmaxf(Ll[wave][quad * 4 + rg], 1e-20f);
    #pragma unroll
    for (int cb = 0; cb < 4; ++cb)
        #pragma unroll
        for (int rg = 0; rg < 4; ++rg) {
            const size_t row = (size_t)(b * TS + q0 + wave * 16 + quad * 4 + rg);
            Out[row * DM + h * 64 + cb * 16 + fn] = f2b(o[cb][rg] * li[rg]);
        }
}

// ---------------------------------------------------------------------------
// Diagnostics (durations @ 100 MHz realtime clock — verified round 8):
//  diag[0]=cat (0 ok|1 diff|2 big|3 inf|4 nan)  diag[1]=min bad row
//  diag[2]=min bad head.  spin_A: ok -> 5ms marker, else cat*20ms+(row+10)*2us.
//  spin_B: ok -> 0, else (head+1)*3ms.
// ---------------------------------------------------------------------------
__global__ void diag_init(int* diag)
{ if (threadIdx.x == 0) { diag[0] = 0; diag[1] = 100000; diag[2] = 100; } }

__global__ __launch_bounds__(256)
void diag_compare(const bf16* __restrict__ mix, const bf16* __restrict__ qkv,
                  int* diag)
{
    const int row = blockIdx.x;
    int cat = 0, badh = 100;
    for (int j = 0; j < 3; ++j) {
        const int col = threadIdx.x + j * 256;
        const float a = b2f(mix[(size_t)row * DM + col]);
        const float bb = b2f(qkv[(size_t)row * 2304 + col]);
        int e = 0;
        if (fabsf(a - bb) > 0.25f) e = 1;
        if (fabsf(a) > 1e3f)       e = 2;
        if (fabsf(a) > 3e38f)      e = 3;
        if (a != a)                e = 4;
        if (e > 0) badh = min(badh, col >> 6);
        cat = max(cat, e);
    }
    if (cat > 0) { atomicMax(&diag[0], cat); atomicMin(&diag[1], row); atomicMin(&diag[2], badh); }
}

__global__ void diag_spin_A(const int* diag)
{
    if (threadIdx.x == 0) {
        const int cat = diag[0];
        unsigned long long n = cat ? (unsigned long long)cat * 2000000ull
                                     + ((unsigned long long)diag[1] + 10ull) * 200ull
                                   : 500000ull;
        unsigned long long t0 = __builtin_amdgcn_s_memrealtime();
        while (__builtin_amdgcn_s_memrealtime() - t0 < n) {}
    }
}
__global__ void diag_spin_B(const int* diag)
{
    if (threadIdx.x == 0) {
        unsigned long long n = diag[0]
            ? ((unsigned long long)diag[2] + 1ull) * 300000ull : 0ull;
        unsigned long long t0 = __builtin_amdgcn_s_memrealtime();
        while (__builtin_amdgcn_s_memrealtime() - t0 < n) {}
    }
}

// ---------------------------------------------------------------------------
__global__ __launch_bounds__(256)
void transW(const float* __restrict__ W, bf16* __restrict__ Wt, int K, int N)
{
    __shared__ float t[32][33];
    const int k0 = blockIdx.x * 32, n0 = blockIdx.y * 32;
    const int tx = threadIdx.x, ty = threadIdx.y;
    #pragma unroll
    for (int i = 0; i < 4; ++i)
        t[ty + i * 8][tx] = W[(size_t)(k0 + ty + i * 8) * N + n0 + tx];
    __syncthreads();
    #pragma unroll
    for (int i = 0; i < 4; ++i)
        Wt[(size_t)(n0 + ty + i * 8) * K + k0 + tx] = f2b(t[tx][ty + i * 8]);
}

__global__ __launch_bounds__(256)
void pack_bias(const float* __restrict__ bq, const float* __restrict__ bk,
               const float* __restrict__ bv, float* __restrict__ out)
{
    const int i = blockIdx.x * 256 + threadIdx.x;
    if (i < 3 * DM)
        out[i] = (i < DM) ? bq[i] : (i < 2 * DM) ? bk[i - DM] : bv[i - 2 * DM];
}

template <typename T1, typename T2, typename TOUT>
__global__ __launch_bounds__(256)
void add_ln(const T1* __restrict__ a, const T2* __restrict__ r, int ldr,
            const float* __restrict__ gamma, const float* __restrict__ beta,
            TOUT* __restrict__ out)
{
    const int row = blockIdx.x;
    const size_t offa = (size_t)row * DM;
    const size_t offr = (size_t)row * ldr;
    const int tid = threadIdx.x;

    float v[3];
    float s = 0.f, s2 = 0.f;
    #pragma unroll
    for (int j = 0; j < 3; ++j) {
        const int i = tid + j * 256;
        const float t = ldf(a + offa + i) + ldf(r + offr + i);
        v[j] = t; s += t; s2 += t * t;
    }
    __shared__ float red[256], red2[256];
    red[tid] = s; red2[tid] = s2;
    __syncthreads();
    #pragma unroll
    for (int st = 128; st > 0; st >>= 1) {
        if (tid < st) { red[tid] += red[tid + st]; red2[tid] += red2[tid + st]; }
        __syncthreads();
    }
    const float mu   = red[0] * (1.f / DM);
    const float var  = red2[0] * (1.f / DM) - mu * mu;
    const float rstd = rsqrtf(var + EPS);
    #pragma unroll
    for (int j = 0; j < 3; ++j) {
        const int i = tid + j * 256;
        stf(out + offa + i, (v[j] - mu) * rstd * gamma[i] + beta[i]);
    }
}

// ---------------------------------------------------------------------------
extern "C" void kernel_launch(void* const* d_in, const int* in_sizes, int n_in,
                              void* d_out, int out_size, void* d_ws, size_t ws_size,
                              hipStream_t stream)
{
    (void)in_sizes; (void)n_in; (void)out_size; (void)ws_size;

    const float* x   = (const float*)d_in[0];
    const float* wq  = (const float*)d_in[1];  const float* bq  = (const float*)d_in[2];
    const float* wk  = (const float*)d_in[3];  const float* bk  = (const float*)d_in[4];
    const float* wv  = (const float*)d_in[5];  const float* bv  = (const float*)d_in[6];
    const float* wo  = (const float*)d_in[7];  const float* bo  = (const float*)d_in[8];
    const float* w1  = (const float*)d_in[9];  const float* b1  = (const float*)d_in[10];
    const float* w2  = (const float*)d_in[11]; const float* b2  = (const float*)d_in[12];
    const float* g1  = (const float*)d_in[13]; const float* be1 = (const float*)d_in[14];
    const float* g2  = (const float*)d_in[15]; const float* be2 = (const float*)d_in[16];

    const size_t S = (size_t)MTOK * DM;
    bf16* QKVb = (bf16*)d_ws;
    bf16* Hb   = QKVb + 3 * S;
    bf16* wbuf = Hb + S;
    float* bqkv = (float*)(wbuf + (size_t)2 * DFF * DM);
    int*  diag = (int*)(bqkv + 3 * DM);
    bf16* F1 = QKVb;
    bf16* Yb = QKVb + 2 * S;
    bf16* AttnO = QKVb;           // Q-band, lda 2304
    bf16* Pb = QKVb + DM;         // K-band

    const dim3 tblk(32, 8);
    const dim3 blk(256);

    // QKV projection
    transW<<<dim3(24, 24), tblk, 0, stream>>>(wq, wbuf,                    DM, DM);
    transW<<<dim3(24, 24), tblk, 0, stream>>>(wk, wbuf + (size_t)DM * DM,  DM, DM);
    transW<<<dim3(24, 24), tblk, 0, stream>>>(wv, wbuf + (size_t)2*DM*DM,  DM, DM);
    pack_bias<<<dim3(9), blk, 0, stream>>>(bq, bk, bv, bqkv);
    gemm_mfma<0, float><<<dim3(18, 64), blk, 0, stream>>>(
        x, DM, wbuf, bqkv, QKVb, 3 * DM, 3 * DM, DM);

    // candidate (reads pristine Q-band, writes Hb)
    attn_v2<<<dim3(64, NB * NH), blk, 0, stream>>>(QKVb, Hb);

    // proven scalar attention -> real pipeline (in-place Q-band)
    attn_scalar<<<dim3(NB * NH * TS), dim3(64), 0, stream>>>(QKVb);

    // compare + encode
    diag_init<<<dim3(1), dim3(64), 0, stream>>>(diag);
    diag_compare<<<dim3(MTOK), blk, 0, stream>>>(Hb, QKVb, diag);
    diag_spin_A<<<dim3(1), dim3(64), 0, stream>>>(diag);
    diag_spin_B<<<dim3(1), dim3(64), 0, stream>>>(diag);

    // O-projection (Q-band -> K-band), LN1 -> Hb (overwrites candidate scratch)
    transW<<<dim3(24, 24), tblk, 0, stream>>>(wo, wbuf, DM, DM);
    gemm_mfma<0, bf16><<<dim3(6, 64), blk, 0, stream>>>(
        AttnO, 3 * DM, wbuf, bo, Pb, 3 * DM, DM, DM);
    add_ln<float, bf16, bf16><<<dim3(MTOK), blk, 0, stream>>>(
        x, Pb, 3 * DM, g1, be1, Hb);

    // FFN
    transW<<<dim3(24, 96), tblk, 0, stream>>>(w1, wbuf, DM, DFF);
    bf16* w2t = wbuf + (size_t)DFF * DM;
    transW<<<dim3(96, 24), tblk, 0, stream>>>(w2, w2t, DFF, DM);
    for (int m0 = 0; m0 < MTOK; m0 += 4096) {
        gemm_mfma<1, bf16><<<dim3(24, 32), blk, 0, stream>>>(
            Hb + (size_t)m0 * DM, DM, wbuf, b1, F1, DFF, DFF, DM);
        gemm_mfma<0, bf16><<<dim3(6, 32), blk, 0, stream>>>(
            F1, DFF, w2t, b2, Yb + (size_t)m0 * DM, DM, DM, DFF);
    }

    add_ln<bf16, bf16, float><<<dim3(MTOK), blk, 0, stream>>>(
        Hb, Yb, DM, g2, be2, (float*)d_out);
}

// Round 10
// 761.057 us; speedup vs baseline: 146.7293x; 133.6704x over previous
//
#include <hip/hip_runtime.h>
#include <hip/hip_bf16.h>

typedef __hip_bfloat16 bf16;
typedef __attribute__((ext_vector_type(8))) short short8;
typedef __attribute__((ext_vector_type(4))) float floatx4;

#define DM   768
#define NH   12
#define DH   64
#define DFF  3072
#define TS   4096
#define NB   2
#define MTOK (NB * TS)
#define EPS  1e-5f
#define NEG  -30000.0f

__device__ __forceinline__ float b2f(bf16 v)  { return __bfloat162float(v); }
__device__ __forceinline__ bf16  f2b(float v) { return __float2bfloat16(v); }
__device__ __forceinline__ short sbf(float x) { bf16 b = __float2bfloat16(x); return *(short*)&b; }
__device__ __forceinline__ float ldf(const float* p) { return *p; }
__device__ __forceinline__ float ldf(const bf16*  p) { return b2f(*p); }
__device__ __forceinline__ void stf(float* p, float v) { *p = v; }
__device__ __forceinline__ void stf(bf16*  p, float v) { *p = f2b(v); }

// ---------------------------------------------------------------------------
// MFMA GEMM (PROVEN round 6).
// ---------------------------------------------------------------------------
template <int RELU, typename TA>
__global__ __launch_bounds__(256)
void gemm_mfma(const TA* __restrict__ A, int lda, const bf16* __restrict__ Wt,
               const float* __restrict__ bias, bf16* __restrict__ C, int ldc,
               int N, int K)
{
    constexpr int LDT = 40;
    __shared__ __align__(16) short As[128 * LDT];
    __shared__ __align__(16) short Bs[128 * LDT];

    const int tid  = threadIdx.x;
    const int wave = tid >> 6, lane = tid & 63;
    const int wx = wave & 1, wy = wave >> 1;
    const int quad = lane >> 4, fn = lane & 15;
    const int bm = blockIdx.y * 128, bn = blockIdx.x * 128;

    floatx4 acc[4][4] = {};
    const int sr = tid >> 2, sc8 = (tid & 3) * 8;

    for (int kk = 0; kk < K; kk += 32) {
        __syncthreads();
        if constexpr (sizeof(TA) == 2) {
            *(short8*)&As[sr * LDT + sc8] =
                *(const short8*)&A[(size_t)(bm + sr) * lda + kk + sc8];
            *(short8*)&As[(sr + 64) * LDT + sc8] =
                *(const short8*)&A[(size_t)(bm + sr + 64) * lda + kk + sc8];
        } else {
            const float* p0 = (const float*)A + (size_t)(bm + sr) * lda + kk + sc8;
            const float* p1 = (const float*)A + (size_t)(bm + sr + 64) * lda + kk + sc8;
            float4 a0 = *(const float4*)p0, a1 = *(const float4*)(p0 + 4);
            float4 c0 = *(const float4*)p1, c1 = *(const float4*)(p1 + 4);
            short8 v0, v1;
            v0[0]=sbf(a0.x); v0[1]=sbf(a0.y); v0[2]=sbf(a0.z); v0[3]=sbf(a0.w);
            v0[4]=sbf(a1.x); v0[5]=sbf(a1.y); v0[6]=sbf(a1.z); v0[7]=sbf(a1.w);
            v1[0]=sbf(c0.x); v1[1]=sbf(c0.y); v1[2]=sbf(c0.z); v1[3]=sbf(c0.w);
            v1[4]=sbf(c1.x); v1[5]=sbf(c1.y); v1[6]=sbf(c1.z); v1[7]=sbf(c1.w);
            *(short8*)&As[sr * LDT + sc8] = v0;
            *(short8*)&As[(sr + 64) * LDT + sc8] = v1;
        }
        *(short8*)&Bs[sr * LDT + sc8] =
            *(const short8*)&Wt[(size_t)(bn + sr) * K + kk + sc8];
        *(short8*)&Bs[(sr + 64) * LDT + sc8] =
            *(const short8*)&Wt[(size_t)(bn + sr + 64) * K + kk + sc8];
        __syncthreads();

        short8 af[4], bfr[4];
        #pragma unroll
        for (int i = 0; i < 4; ++i) {
            af[i]  = *(const short8*)&As[(wy * 64 + i * 16 + fn) * LDT + quad * 8];
            bfr[i] = *(const short8*)&Bs[(wx * 64 + i * 16 + fn) * LDT + quad * 8];
        }
        #pragma unroll
        for (int i = 0; i < 4; ++i)
            #pragma unroll
            for (int j = 0; j < 4; ++j)
                acc[i][j] = __builtin_amdgcn_mfma_f32_16x16x32_bf16(
                    af[i], bfr[j], acc[i][j], 0, 0, 0);
    }

    #pragma unroll
    for (int j = 0; j < 4; ++j) {
        const int n = bn + wx * 64 + j * 16 + fn;
        const float bv = bias[n];
        #pragma unroll
        for (int i = 0; i < 4; ++i) {
            #pragma unroll
            for (int rg = 0; rg < 4; ++rg) {
                const int m = bm + wy * 64 + i * 16 + quad * 4 + rg;
                float v = acc[i][j][rg] + bv;
                if (RELU) v = fmaxf(v, 0.f);
                C[(size_t)m * ldc + n] = f2b(v);
            }
        }
    }
}

// ---------------------------------------------------------------------------
// MFMA flash attention (attn_v2 + ROOT-CAUSE FIX).
// Root cause of rounds 4-9 NaN: `Vt[..] = QKV[..]` was an implicit
// bf16 -> float -> short NUMERIC conversion; V <= -1 truncated to short
// -1/-2/... = 0xFFFF/0xFFFE = bf16 NaN bit patterns fed to the PV MFMA.
// Fix: bit-copy via (const short*). Everything else unchanged from the
// round-9 candidate (MFMA QK^T -> LDS -> LDS softmax -> P LDS -> PV MFMA).
// ---------------------------------------------------------------------------
__global__ __launch_bounds__(256)
void attn_v2(const bf16* __restrict__ QKV, bf16* __restrict__ Out)
{
    __shared__ __align__(16) short Ks[32 * 72];      // [key][d]
    __shared__ __align__(16) short Vt[64 * 40];      // [d][key]
    __shared__ __align__(16) float Ss[4][16 * 36];   // per-wave S [q][key] fp32
    __shared__ __align__(16) short Ps[4][16 * 40];   // per-wave P [q][key] bf16
    __shared__ float Al[4][16];                      // per-row alpha
    __shared__ float Ll[4][16];                      // per-row l

    const int tid  = threadIdx.x;
    const int wave = tid >> 6, lane = tid & 63;
    const int quad = lane >> 4, fn = lane & 15;
    const int bh = blockIdx.y;
    const int b = bh / NH, h = bh % NH;
    const int q0 = (gridDim.x - 1 - blockIdx.x) * 64;
    const int nt = q0 / 32 + 2;

    const int orow = lane >> 2;
    const int okey = (lane & 3) * 8;

    const short* QKVs = (const short*)QKV;   // bit view for LDS staging

    const size_t rowQ = (size_t)(b * TS + q0 + wave * 16 + fn) * 2304 + h * 64;
    const short8 qa0 = *(const short8*)&QKV[rowQ + quad * 8];
    const short8 qa1 = *(const short8*)&QKV[rowQ + 32 + quad * 8];

    float mrow = NEG, lrow = 0.f;
    floatx4 o[4] = {};

    const int sk = tid >> 3, sc8 = (tid & 7) * 8;
    const int vd = tid & 63, vk0 = tid >> 6;

    for (int t = 0; t < nt; ++t) {
        const int kk0 = t * 32;
        __syncthreads();
        *(short8*)&Ks[sk * 72 + sc8] =
            *(const short8*)&QKV[(size_t)(b * TS + kk0 + sk) * 2304 + 768 + h * 64 + sc8];
        #pragma unroll
        for (int i = 0; i < 8; ++i) {
            const int k = vk0 + i * 4;
            Vt[vd * 40 + k] =                       // FIXED: bit copy, not numeric cast
                QKVs[(size_t)(b * TS + kk0 + k) * 2304 + 1536 + h * 64 + vd];
        }
        __syncthreads();

        // S = Q K^T (MFMA)
        const short8 b00 = *(const short8*)&Ks[fn * 72 + quad * 8];
        const short8 b01 = *(const short8*)&Ks[fn * 72 + 32 + quad * 8];
        const short8 b10 = *(const short8*)&Ks[(16 + fn) * 72 + quad * 8];
        const short8 b11 = *(const short8*)&Ks[(16 + fn) * 72 + 32 + quad * 8];
        floatx4 s0 = {}, s1 = {};
        s0 = __builtin_amdgcn_mfma_f32_16x16x32_bf16(qa0, b00, s0, 0, 0, 0);
        s0 = __builtin_amdgcn_mfma_f32_16x16x32_bf16(qa1, b01, s0, 0, 0, 0);
        s1 = __builtin_amdgcn_mfma_f32_16x16x32_bf16(qa0, b10, s1, 0, 0, 0);
        s1 = __builtin_amdgcn_mfma_f32_16x16x32_bf16(qa1, b11, s1, 0, 0, 0);

        // scale + mask in VALU, S -> LDS
        const int qg = q0 + wave * 16 + quad * 4;
        #pragma unroll
        for (int rg = 0; rg < 4; ++rg) {
            const float v0 = (kk0 + fn      <= qg + rg) ? s0[rg] * 0.125f : NEG;
            const float v1 = (kk0 + 16 + fn <= qg + rg) ? s1[rg] * 0.125f : NEG;
            Ss[wave][(quad * 4 + rg) * 36 + fn]      = v0;
            Ss[wave][(quad * 4 + rg) * 36 + 16 + fn] = v1;
        }
        __syncthreads();

        // LDS softmax (lane owns row lane>>2, 8-key slice)
        float sv[8];
        *(float4*)&sv[0] = *(const float4*)&Ss[wave][orow * 36 + okey];
        *(float4*)&sv[4] = *(const float4*)&Ss[wave][orow * 36 + okey + 4];
        float mx = sv[0];
        #pragma unroll
        for (int j = 1; j < 8; ++j) mx = fmaxf(mx, sv[j]);
        mx = fmaxf(mx, __shfl_xor(mx, 1, 64));
        mx = fmaxf(mx, __shfl_xor(mx, 2, 64));
        const float mn2 = fmaxf(mrow, mx);
        float ps = 0.f;
        short8 pb;
        #pragma unroll
        for (int j = 0; j < 8; ++j) {
            const float p = __expf(fminf(sv[j] - mn2, 0.f));
            ps += p;
            pb[j] = sbf(p);
        }
        ps += __shfl_xor(ps, 1, 64);
        ps += __shfl_xor(ps, 2, 64);
        const float cr = __expf(fminf(mrow - mn2, 0.f));
        lrow = lrow * cr + ps;
        mrow = mn2;
        *(short8*)&Ps[wave][orow * 40 + okey] = pb;
        if ((lane & 3) == 0) { Al[wave][orow] = cr; Ll[wave][orow] = lrow; }
        __syncthreads();

        // rescale accumulator (alpha from LDS) + PV MFMA
        float al[4];
        #pragma unroll
        for (int rg = 0; rg < 4; ++rg) al[rg] = Al[wave][quad * 4 + rg];
        #pragma unroll
        for (int cb = 0; cb < 4; ++cb)
            #pragma unroll
            for (int rg = 0; rg < 4; ++rg) o[cb][rg] *= al[rg];
        const short8 pf = *(const short8*)&Ps[wave][fn * 40 + quad * 8];
        #pragma unroll
        for (int cb = 0; cb < 4; ++cb) {
            const short8 vf = *(const short8*)&Vt[(cb * 16 + fn) * 40 + quad * 8];
            o[cb] = __builtin_amdgcn_mfma_f32_16x16x32_bf16(pf, vf, o[cb], 0, 0, 0);
        }
    }

    float li[4];
    #pragma unroll
    for (int rg = 0; rg < 4; ++rg)
        li[rg] = 1.f / fmaxf(Ll[wave][quad * 4 + rg], 1e-20f);
    #pragma unroll
    for (int cb = 0; cb < 4; ++cb)
        #pragma unroll
        for (int rg = 0; rg < 4; ++rg) {
            const size_t row = (size_t)(b * TS + q0 + wave * 16 + quad * 4 + rg);
            Out[row * DM + h * 64 + cb * 16 + fn] = f2b(o[cb][rg] * li[rg]);
        }
}

// ---------------------------------------------------------------------------
__global__ __launch_bounds__(256)
void transW(const float* __restrict__ W, bf16* __restrict__ Wt, int K, int N)
{
    __shared__ float t[32][33];
    const int k0 = blockIdx.x * 32, n0 = blockIdx.y * 32;
    const int tx = threadIdx.x, ty = threadIdx.y;
    #pragma unroll
    for (int i = 0; i < 4; ++i)
        t[ty + i * 8][tx] = W[(size_t)(k0 + ty + i * 8) * N + n0 + tx];
    __syncthreads();
    #pragma unroll
    for (int i = 0; i < 4; ++i)
        Wt[(size_t)(n0 + ty + i * 8) * K + k0 + tx] = f2b(t[tx][ty + i * 8]);
}

__global__ __launch_bounds__(256)
void pack_bias(const float* __restrict__ bq, const float* __restrict__ bk,
               const float* __restrict__ bv, float* __restrict__ out)
{
    const int i = blockIdx.x * 256 + threadIdx.x;
    if (i < 3 * DM)
        out[i] = (i < DM) ? bq[i] : (i < 2 * DM) ? bk[i - DM] : bv[i - 2 * DM];
}

template <typename T1, typename T2, typename TOUT>
__global__ __launch_bounds__(256)
void add_ln(const T1* __restrict__ a, const T2* __restrict__ r, int ldr,
            const float* __restrict__ gamma, const float* __restrict__ beta,
            TOUT* __restrict__ out)
{
    const int row = blockIdx.x;
    const size_t offa = (size_t)row * DM;
    const size_t offr = (size_t)row * ldr;
    const int tid = threadIdx.x;

    float v[3];
    float s = 0.f, s2 = 0.f;
    #pragma unroll
    for (int j = 0; j < 3; ++j) {
        const int i = tid + j * 256;
        const float t = ldf(a + offa + i) + ldf(r + offr + i);
        v[j] = t; s += t; s2 += t * t;
    }
    __shared__ float red[256], red2[256];
    red[tid] = s; red2[tid] = s2;
    __syncthreads();
    #pragma unroll
    for (int st = 128; st > 0; st >>= 1) {
        if (tid < st) { red[tid] += red[tid + st]; red2[tid] += red2[tid + st]; }
        __syncthreads();
    }
    const float mu   = red[0] * (1.f / DM);
    const float var  = red2[0] * (1.f / DM) - mu * mu;
    const float rstd = rsqrtf(var + EPS);
    #pragma unroll
    for (int j = 0; j < 3; ++j) {
        const int i = tid + j * 256;
        stf(out + offa + i, (v[j] - mu) * rstd * gamma[i] + beta[i]);
    }
}

// ---------------------------------------------------------------------------
extern "C" void kernel_launch(void* const* d_in, const int* in_sizes, int n_in,
                              void* d_out, int out_size, void* d_ws, size_t ws_size,
                              hipStream_t stream)
{
    (void)in_sizes; (void)n_in; (void)out_size; (void)ws_size;

    const float* x   = (const float*)d_in[0];
    const float* wq  = (const float*)d_in[1];  const float* bq  = (const float*)d_in[2];
    const float* wk  = (const float*)d_in[3];  const float* bk  = (const float*)d_in[4];
    const float* wv  = (const float*)d_in[5];  const float* bv  = (const float*)d_in[6];
    const float* wo  = (const float*)d_in[7];  const float* bo  = (const float*)d_in[8];
    const float* w1  = (const float*)d_in[9];  const float* b1  = (const float*)d_in[10];
    const float* w2  = (const float*)d_in[11]; const float* b2  = (const float*)d_in[12];
    const float* g1  = (const float*)d_in[13]; const float* be1 = (const float*)d_in[14];
    const float* g2  = (const float*)d_in[15]; const float* be2 = (const float*)d_in[16];

    // ws layout (bf16 elems), ~59.8 MB (proven round 6):
    //   QKVb [8192][2304] = 3S | Hb = S | wbuf = 2*DFF*DM | bqkv fp32[2304]
    const size_t S = (size_t)MTOK * DM;
    bf16* QKVb = (bf16*)d_ws;
    bf16* Hb   = QKVb + 3 * S;
    bf16* wbuf = Hb + S;
    float* bqkv = (float*)(wbuf + (size_t)2 * DFF * DM);
    bf16* F1 = QKVb;              // FFN hidden chunk [4096][3072]
    bf16* Yb = QKVb + 2 * S;      // FFN out
    bf16* Pb = QKVb + DM;         // O-proj out -> K-band (dead), ld 2304
    bf16* Ao = Hb;                // attention out (dense; Hb free until LN1)

    const dim3 tblk(32, 8);
    const dim3 blk(256);

    // QKV projection
    transW<<<dim3(24, 24), tblk, 0, stream>>>(wq, wbuf,                    DM, DM);
    transW<<<dim3(24, 24), tblk, 0, stream>>>(wk, wbuf + (size_t)DM * DM,  DM, DM);
    transW<<<dim3(24, 24), tblk, 0, stream>>>(wv, wbuf + (size_t)2*DM*DM,  DM, DM);
    pack_bias<<<dim3(9), blk, 0, stream>>>(bq, bk, bv, bqkv);
    gemm_mfma<0, float><<<dim3(18, 64), blk, 0, stream>>>(
        x, DM, wbuf, bqkv, QKVb, 3 * DM, 3 * DM, DM);

    // MFMA flash attention -> Ao (dense 768)
    attn_v2<<<dim3(64, NB * NH), blk, 0, stream>>>(QKVb, Ao);

    // O-projection (Ao -> K-band), LN1 -> Hb (overwrites Ao after read)
    transW<<<dim3(24, 24), tblk, 0, stream>>>(wo, wbuf, DM, DM);
    gemm_mfma<0, bf16><<<dim3(6, 64), blk, 0, stream>>>(
        Ao, DM, wbuf, bo, Pb, 3 * DM, DM, DM);
    add_ln<float, bf16, bf16><<<dim3(MTOK), blk, 0, stream>>>(
        x, Pb, 3 * DM, g1, be1, Hb);

    // FFN (chunked over M; F1/Yb live in the dead QKVb region)
    transW<<<dim3(24, 96), tblk, 0, stream>>>(w1, wbuf, DM, DFF);
    bf16* w2t = wbuf + (size_t)DFF * DM;
    transW<<<dim3(96, 24), tblk, 0, stream>>>(w2, w2t, DFF, DM);
    for (int m0 = 0; m0 < MTOK; m0 += 4096) {
        gemm_mfma<1, bf16><<<dim3(24, 32), blk, 0, stream>>>(
            Hb + (size_t)m0 * DM, DM, wbuf, b1, F1, DFF, DFF, DM);
        gemm_mfma<0, bf16><<<dim3(6, 32), blk, 0, stream>>>(
            F1, DFF, w2t, b2, Yb + (size_t)m0 * DM, DM, DM, DFF);
    }

    add_ln<bf16, bf16, float><<<dim3(MTOK), blk, 0, stream>>>(
        Hb, Yb, DM, g2, be2, (float*)d_out);
}